// Round 1
// baseline (104.035 us; speedup 1.0000x reference)
//
#include <hip/hip_runtime.h>
#include <stdint.h>

typedef unsigned short u16;
typedef unsigned int u32;

#define NTOT 8192          // 2B rows
#define BH   4096          // B
#define DD   128           // feature dim
#define COLSPLIT 8
#define COLS_PER_SPLIT (NTOT / COLSPLIT)   // 1024
#define TILE_COLS 128
#define TILES_PER_SPLIT (COLS_PER_SPLIT / TILE_COLS) // 8
#define ROWS_PER_BLOCK 128
#define ROWS_PER_WAVE 32
#define LDS_PITCH 136      // 128 + 8 bf16 pad -> 2-way bank aliasing (free)
#define NEG_INF (-3.0e38f)
#define SCALE_IN 2.68579144f   // sqrt(log2(e)/0.2): MFMA output is sim*log2(e) -> exp2 domain
#define LN2F 0.6931471805599453f

typedef __bf16 bf16x8 __attribute__((ext_vector_type(8)));
typedef float  f32x4  __attribute__((ext_vector_type(4)));

__device__ __forceinline__ u16 f2bf(float f) {
  u32 u = __float_as_uint(f);
  return (u16)((u + 0x7fffu + ((u >> 16) & 1u)) >> 16);  // RNE
}

// ---- kernel 1: fp32 z1,z2 -> scaled bf16 zb[8192][128] -------------------
__global__ __launch_bounds__(256) void ntx_convert(
    const float* __restrict__ z1, const float* __restrict__ z2,
    u16* __restrict__ zb) {
  const int i = (blockIdx.x * 256 + threadIdx.x) * 4;   // 1024 blocks cover 1,048,576 floats
  const int half = BH * DD;
  float4 v = (i < half) ? *reinterpret_cast<const float4*>(z1 + i)
                        : *reinterpret_cast<const float4*>(z2 + (i - half));
  u32 lo = (u32)f2bf(v.x * SCALE_IN) | ((u32)f2bf(v.y * SCALE_IN) << 16);
  u32 hi = (u32)f2bf(v.z * SCALE_IN) | ((u32)f2bf(v.w * SCALE_IN) << 16);
  uint2 o; o.x = lo; o.y = hi;
  *reinterpret_cast<uint2*>(zb + i) = o;
}

// ---- kernel 2: flash-style row logsumexp over a col-split ----------------
// grid = (64 rowblocks, 8 colsplits), block = 256 (4 waves x 32 rows)
__global__ __launch_bounds__(256, 2) void ntx_main(
    const u16* __restrict__ zb,
    float* __restrict__ m_part, float* __restrict__ l_part,
    float* __restrict__ st_part) {
  __shared__ u16 lds_tile[TILE_COLS * LDS_PITCH];  // 34,816 B

  const int tid  = threadIdx.x;
  const int wave = tid >> 6;
  const int lane = tid & 63;
  const int l15  = lane & 15;
  const int q    = lane >> 4;

  const int rwave = blockIdx.x * ROWS_PER_BLOCK + wave * ROWS_PER_WAVE;
  const int split = blockIdx.y;
  const int col0  = split * COLS_PER_SPLIT;

  // A-fragments for this wave's 32 rows, kept in registers the whole kernel.
  // 16x16x32 bf16 A layout: row = lane&15, k = (lane>>4)*8 + j  (m120-verified)
  bf16x8 afrag[2][4];
#pragma unroll
  for (int rt = 0; rt < 2; ++rt)
#pragma unroll
    for (int kk = 0; kk < 4; ++kk) {
      const int r = rwave + rt * 16 + l15;
      afrag[rt][kk] = *reinterpret_cast<const bf16x8*>(zb + r * DD + kk * 32 + q * 8);
    }

  float m_run[2][4], l_run[2][4], stv[2][4];
#pragma unroll
  for (int rt = 0; rt < 2; ++rt)
#pragma unroll
    for (int r = 0; r < 4; ++r) { m_run[rt][r] = NEG_INF; l_run[rt][r] = 0.f; stv[rt][r] = NEG_INF; }

  for (int t = 0; t < TILES_PER_SPLIT; ++t) {
    const int ct0 = col0 + t * TILE_COLS;

    __syncthreads();   // previous tile's compute done before overwrite
    {
      // stage 128 cols x 128 k (bf16) -> LDS with +8 pitch pad.
      // source is one contiguous 32KB block; 2048 16B chunks, 8 per thread.
      const uint4* src = reinterpret_cast<const uint4*>(zb + ct0 * DD);
#pragma unroll
      for (int i = 0; i < 8; ++i) {
        const int c   = tid + i * 256;
        const int col = c >> 4, w16 = c & 15;
        uint4 v = src[c];
        *reinterpret_cast<uint4*>(lds_tile + col * LDS_PITCH + w16 * 8) = v;
      }
    }
    __syncthreads();

    // ---- GEMM: 32 rows x 128 cols x K=128 per wave ----
    f32x4 acc[2][8];
#pragma unroll
    for (int rt = 0; rt < 2; ++rt)
#pragma unroll
      for (int cs = 0; cs < 8; ++cs) acc[rt][cs] = (f32x4){0.f, 0.f, 0.f, 0.f};

#pragma unroll
    for (int cs = 0; cs < 8; ++cs) {
      bf16x8 bfrag[4];
#pragma unroll
      for (int kk = 0; kk < 4; ++kk)
        bfrag[kk] = *reinterpret_cast<const bf16x8*>(
            lds_tile + (cs * 16 + l15) * LDS_PITCH + kk * 32 + q * 8);
#pragma unroll
      for (int rt = 0; rt < 2; ++rt)
#pragma unroll
        for (int kk = 0; kk < 4; ++kk)
          acc[rt][cs] = __builtin_amdgcn_mfma_f32_16x16x32_bf16(
              afrag[rt][kk], bfrag[kk], acc[rt][cs], 0, 0, 0);
    }

    // ---- diag mask + target extraction (only in the <=2 tiles that need it) ----
    const bool has_diag = (rwave >= ct0) && (rwave < ct0 + TILE_COLS);
    const int  trow     = rwave ^ BH;
    const bool has_tgt  = (trow >= ct0) && (trow < ct0 + TILE_COLS);
    if (has_diag || has_tgt) {
#pragma unroll
      for (int rt = 0; rt < 2; ++rt)
#pragma unroll
        for (int r = 0; r < 4; ++r) {
          const int grow = rwave + rt * 16 + q * 4 + r;  // C layout: row=(lane>>4)*4+reg
#pragma unroll
          for (int cs = 0; cs < 8; ++cs) {
            const int gcol = ct0 + cs * 16 + l15;        // C layout: col=lane&15
            float v = acc[rt][cs][r];
            if (gcol == (grow ^ BH)) stv[rt][r] = fmaxf(stv[rt][r], v);
            if (gcol == grow) acc[rt][cs][r] = NEG_INF;
          }
        }
    }

    // ---- online logsumexp update (batched over the 128-col tile) ----
#pragma unroll
    for (int rt = 0; rt < 2; ++rt)
#pragma unroll
      for (int r = 0; r < 4; ++r) {
        float mx = acc[rt][0][r];
#pragma unroll
        for (int cs = 1; cs < 8; ++cs) mx = fmaxf(mx, acc[rt][cs][r]);
#pragma unroll
        for (int off = 8; off >= 1; off >>= 1) mx = fmaxf(mx, __shfl_xor(mx, off, 64));
        const float mnew  = fmaxf(m_run[rt][r], mx);
        const float alpha = exp2f(m_run[rt][r] - mnew);   // exp2: scale folded into inputs
        float s = 0.f;
#pragma unroll
        for (int cs = 0; cs < 8; ++cs) s += exp2f(acc[rt][cs][r] - mnew);
#pragma unroll
        for (int off = 8; off >= 1; off >>= 1) s += __shfl_xor(s, off, 64);
        l_run[rt][r] = l_run[rt][r] * alpha + s;
        m_run[rt][r] = mnew;
      }
  }

  // ---- write per-(row, split) partials ----
#pragma unroll
  for (int rt = 0; rt < 2; ++rt)
#pragma unroll
    for (int r = 0; r < 4; ++r) {
      float sv = stv[rt][r];
#pragma unroll
      for (int off = 8; off >= 1; off >>= 1) sv = fmaxf(sv, __shfl_xor(sv, off, 64));
      if (l15 == 0) {
        const int grow = rwave + rt * 16 + q * 4 + r;
        m_part[split * NTOT + grow] = m_run[rt][r];
        l_part[split * NTOT + grow] = l_run[rt][r];
        const int tcol = grow ^ BH;
        if (tcol >= col0 && tcol < col0 + COLS_PER_SPLIT) st_part[grow] = sv;  // exactly one writer/row
      }
    }
}

// ---- kernel 3: combine splits, mean, atomicAdd --------------------------
__global__ __launch_bounds__(256) void ntx_finish(
    const float* __restrict__ m_part, const float* __restrict__ l_part,
    const float* __restrict__ st_part, float* __restrict__ out) {
  const int row = blockIdx.x * 256 + threadIdx.x;   // 32 blocks
  float m = NEG_INF;
#pragma unroll
  for (int s = 0; s < COLSPLIT; ++s) m = fmaxf(m, m_part[s * NTOT + row]);
  float l = 0.f;
#pragma unroll
  for (int s = 0; s < COLSPLIT; ++s) l += l_part[s * NTOT + row] * exp2f(m_part[s * NTOT + row] - m);
  float loss = LN2F * (m + __log2f(l) - st_part[row]);  // back to natural-log domain

#pragma unroll
  for (int off = 32; off >= 1; off >>= 1) loss += __shfl_xor(loss, off, 64);
  __shared__ float wsum[4];
  if ((threadIdx.x & 63) == 0) wsum[threadIdx.x >> 6] = loss;
  __syncthreads();
  if (threadIdx.x == 0) {
    float s = wsum[0] + wsum[1] + wsum[2] + wsum[3];
    atomicAdd(out, s * (1.0f / NTOT));
  }
}

extern "C" void kernel_launch(void* const* d_in, const int* in_sizes, int n_in,
                              void* d_out, int out_size, void* d_ws, size_t ws_size,
                              hipStream_t stream) {
  const float* z1 = (const float*)d_in[0];
  const float* z2 = (const float*)d_in[1];
  float* out = (float*)d_out;

  // workspace: zb (2MB bf16) | m_part[8][8192] | l_part[8][8192] | st[8192]
  char* ws = (char*)d_ws;
  u16*   zb      = (u16*)ws;
  float* m_part  = (float*)(ws + (size_t)NTOT * DD * 2);
  float* l_part  = m_part + COLSPLIT * NTOT;
  float* st_part = l_part + COLSPLIT * NTOT;

  hipMemsetAsync(d_out, 0, sizeof(float), stream);  // d_out is poisoned each launch

  ntx_convert<<<dim3((NTOT * DD) / (256 * 4)), dim3(256), 0, stream>>>(z1, z2, zb);
  ntx_main<<<dim3(NTOT / ROWS_PER_BLOCK, COLSPLIT), dim3(256), 0, stream>>>(
      zb, m_part, l_part, st_part);
  ntx_finish<<<dim3(NTOT / 256), dim3(256), 0, stream>>>(m_part, l_part, st_part, out);
}

// Round 2
// 86.057 us; speedup vs baseline: 1.2089x; 1.2089x over previous
//
#include <hip/hip_runtime.h>
#include <stdint.h>

typedef unsigned short u16;
typedef unsigned int u32;

#define NTOT 8192          // 2B rows
#define BH   4096          // B
#define DD   128           // feature dim
#define COLSPLIT 8
#define COLS_PER_SPLIT (NTOT / COLSPLIT)   // 1024
#define TILE_COLS 128
#define TILES_PER_SPLIT (COLS_PER_SPLIT / TILE_COLS) // 8
#define ROWS_PER_BLOCK 128
#define ROWS_PER_WAVE 32
#define LDS_PITCH 136      // 128 + 8 bf16 pad; even 8-per-bank distribution for b128 reads
#define NEG_INF (-3.0e38f)
#define SCALE_IN 2.68579144f   // sqrt(log2(e)/0.2): MFMA output is sim*log2(e) -> exp2 domain
#define LN2F 0.6931471805599453f

typedef __bf16 bf16x8 __attribute__((ext_vector_type(8)));
typedef float  f32x4  __attribute__((ext_vector_type(4)));

__device__ __forceinline__ u16 f2bf(float f) {
  u32 u = __float_as_uint(f);
  return (u16)((u + 0x7fffu + ((u >> 16) & 1u)) >> 16);  // RNE
}

// single-instruction v_exp_f32 (avoid OCML multi-instruction exp2f)
__device__ __forceinline__ float fexp2(float x) {
#if __has_builtin(__builtin_amdgcn_exp2f)
  return __builtin_amdgcn_exp2f(x);
#else
  float r; asm("v_exp_f32 %0, %1" : "=v"(r) : "v"(x)); return r;
#endif
}

// ---- kernel 1: fp32 z1,z2 -> scaled bf16 zb[8192][128]; also zero d_out ---
__global__ __launch_bounds__(256) void ntx_convert(
    const float* __restrict__ z1, const float* __restrict__ z2,
    u16* __restrict__ zb, float* __restrict__ out) {
  if (blockIdx.x == 0 && threadIdx.x == 0) out[0] = 0.f;  // replaces memset node
  const int i = (blockIdx.x * 256 + threadIdx.x) * 4;   // 1024 blocks cover 1,048,576 floats
  const int half = BH * DD;
  float4 v = (i < half) ? *reinterpret_cast<const float4*>(z1 + i)
                        : *reinterpret_cast<const float4*>(z2 + (i - half));
  u32 lo = (u32)f2bf(v.x * SCALE_IN) | ((u32)f2bf(v.y * SCALE_IN) << 16);
  u32 hi = (u32)f2bf(v.z * SCALE_IN) | ((u32)f2bf(v.w * SCALE_IN) << 16);
  uint2 o; o.x = lo; o.y = hi;
  *reinterpret_cast<uint2*>(zb + i) = o;
}

// ---- kernel 2: flash-style row logsumexp over a col-split ----------------
// grid = (64 rowblocks, 8 colsplits), block = 256 (4 waves x 32 rows)
// KEY CHANGE vs round 1: online-softmax state (m,l) is PER-LANE (each lane
// covers its fixed 16-lane slice of the row); cross-lane logsumexp merge is
// done ONCE at the end. No per-tile shuffles, no dependent LDS round-trips.
__global__ __launch_bounds__(256, 2) void ntx_main(
    const u16* __restrict__ zb,
    float* __restrict__ m_part, float* __restrict__ l_part,
    float* __restrict__ st_part) {
  __shared__ u16 lds_tile[TILE_COLS * LDS_PITCH];  // 34,816 B

  const int tid  = threadIdx.x;
  const int wave = tid >> 6;
  const int lane = tid & 63;
  const int l15  = lane & 15;
  const int q    = lane >> 4;

  const int rwave = blockIdx.x * ROWS_PER_BLOCK + wave * ROWS_PER_WAVE;
  const int split = blockIdx.y;
  const int col0  = split * COLS_PER_SPLIT;

  // A-fragments: 16x16x32 bf16 A layout: row = lane&15, k = (lane>>4)*8 + j
  bf16x8 afrag[2][4];
#pragma unroll
  for (int rt = 0; rt < 2; ++rt)
#pragma unroll
    for (int kk = 0; kk < 4; ++kk) {
      const int r = rwave + rt * 16 + l15;
      afrag[rt][kk] = *reinterpret_cast<const bf16x8*>(zb + r * DD + kk * 32 + q * 8);
    }

  float m_run[2][4], l_run[2][4], stv[2][4];
#pragma unroll
  for (int rt = 0; rt < 2; ++rt)
#pragma unroll
    for (int r = 0; r < 4; ++r) { m_run[rt][r] = NEG_INF; l_run[rt][r] = 0.f; stv[rt][r] = NEG_INF; }

  for (int t = 0; t < TILES_PER_SPLIT; ++t) {
    const int ct0 = col0 + t * TILE_COLS;

    __syncthreads();   // previous tile's compute done before overwrite
    {
      // stage 128 cols x 128 k (bf16) -> LDS with +8 pitch pad.
      const uint4* src = reinterpret_cast<const uint4*>(zb + ct0 * DD);
#pragma unroll
      for (int i = 0; i < 8; ++i) {
        const int c   = tid + i * 256;
        const int col = c >> 4, w16 = c & 15;
        uint4 v = src[c];
        *reinterpret_cast<uint4*>(lds_tile + col * LDS_PITCH + w16 * 8) = v;
      }
    }
    __syncthreads();

    // ---- GEMM: 32 rows x 128 cols x K=128 per wave ----
    f32x4 acc[2][8];
#pragma unroll
    for (int rt = 0; rt < 2; ++rt)
#pragma unroll
      for (int cs = 0; cs < 8; ++cs) acc[rt][cs] = (f32x4){0.f, 0.f, 0.f, 0.f};

#pragma unroll
    for (int cs = 0; cs < 8; ++cs) {
      bf16x8 bfrag[4];
#pragma unroll
      for (int kk = 0; kk < 4; ++kk)
        bfrag[kk] = *reinterpret_cast<const bf16x8*>(
            lds_tile + (cs * 16 + l15) * LDS_PITCH + kk * 32 + q * 8);
#pragma unroll
      for (int rt = 0; rt < 2; ++rt)
#pragma unroll
        for (int kk = 0; kk < 4; ++kk)
          acc[rt][cs] = __builtin_amdgcn_mfma_f32_16x16x32_bf16(
              afrag[rt][kk], bfrag[kk], acc[rt][cs], 0, 0, 0);
    }

    // ---- diag mask + target extraction (only in the <=2 tiles that need it) ----
    const bool has_diag = (rwave >= ct0) && (rwave < ct0 + TILE_COLS);
    const int  trow     = rwave ^ BH;
    const bool has_tgt  = (trow >= ct0) && (trow < ct0 + TILE_COLS);
    if (has_diag || has_tgt) {
#pragma unroll
      for (int rt = 0; rt < 2; ++rt)
#pragma unroll
        for (int r = 0; r < 4; ++r) {
          const int grow = rwave + rt * 16 + q * 4 + r;  // C layout: row=(lane>>4)*4+reg
#pragma unroll
          for (int cs = 0; cs < 8; ++cs) {
            const int gcol = ct0 + cs * 16 + l15;        // C layout: col=lane&15
            float v = acc[rt][cs][r];
            if (gcol == (grow ^ BH)) stv[rt][r] = fmaxf(stv[rt][r], v);
            if (gcol == grow) acc[rt][cs][r] = NEG_INF;
          }
        }
    }

    // ---- per-lane online logsumexp update (NO cross-lane traffic) ----
#pragma unroll
    for (int rt = 0; rt < 2; ++rt)
#pragma unroll
      for (int r = 0; r < 4; ++r) {
        float mx = acc[rt][0][r];
#pragma unroll
        for (int cs = 1; cs < 8; ++cs) mx = fmaxf(mx, acc[rt][cs][r]);
        const float mnew = fmaxf(m_run[rt][r], mx);
        float s = 0.f;
#pragma unroll
        for (int cs = 0; cs < 8; ++cs) s += fexp2(acc[rt][cs][r] - mnew);
        l_run[rt][r] = l_run[rt][r] * fexp2(m_run[rt][r] - mnew) + s;
        m_run[rt][r] = mnew;
      }
  }

  // ---- one-time cross-lane logsumexp merge over the 16-lane row slice ----
#pragma unroll
  for (int rt = 0; rt < 2; ++rt)
#pragma unroll
    for (int r = 0; r < 4; ++r) {
      float m = m_run[rt][r], l = l_run[rt][r];
#pragma unroll
      for (int off = 1; off < 16; off <<= 1) {
        const float mo = __shfl_xor(m, off, 64);
        const float lo = __shfl_xor(l, off, 64);
        const float mn = fmaxf(m, mo);
        l = l * fexp2(m - mn) + lo * fexp2(mo - mn);
        m = mn;
      }
      float sv = stv[rt][r];
#pragma unroll
      for (int off = 1; off < 16; off <<= 1) sv = fmaxf(sv, __shfl_xor(sv, off, 64));
      if (l15 == 0) {
        const int grow = rwave + rt * 16 + q * 4 + r;
        m_part[split * NTOT + grow] = m;
        l_part[split * NTOT + grow] = l;
        const int tcol = grow ^ BH;
        if (tcol >= col0 && tcol < col0 + COLS_PER_SPLIT) st_part[grow] = sv;  // one writer/row
      }
    }
}

// ---- kernel 3: combine splits, mean, atomicAdd --------------------------
__global__ __launch_bounds__(256) void ntx_finish(
    const float* __restrict__ m_part, const float* __restrict__ l_part,
    const float* __restrict__ st_part, float* __restrict__ out) {
  const int row = blockIdx.x * 256 + threadIdx.x;   // 32 blocks
  float m = NEG_INF;
#pragma unroll
  for (int s = 0; s < COLSPLIT; ++s) m = fmaxf(m, m_part[s * NTOT + row]);
  float l = 0.f;
#pragma unroll
  for (int s = 0; s < COLSPLIT; ++s) l += l_part[s * NTOT + row] * fexp2(m_part[s * NTOT + row] - m);
  float loss = LN2F * (m + __log2f(l) - st_part[row]);  // back to natural-log domain

#pragma unroll
  for (int off = 32; off >= 1; off >>= 1) loss += __shfl_xor(loss, off, 64);
  __shared__ float wsum[4];
  if ((threadIdx.x & 63) == 0) wsum[threadIdx.x >> 6] = loss;
  __syncthreads();
  if (threadIdx.x == 0) {
    float s = wsum[0] + wsum[1] + wsum[2] + wsum[3];
    atomicAdd(out, s * (1.0f / NTOT));
  }
}

extern "C" void kernel_launch(void* const* d_in, const int* in_sizes, int n_in,
                              void* d_out, int out_size, void* d_ws, size_t ws_size,
                              hipStream_t stream) {
  const float* z1 = (const float*)d_in[0];
  const float* z2 = (const float*)d_in[1];
  float* out = (float*)d_out;

  // workspace: zb (2MB bf16) | m_part[8][8192] | l_part[8][8192] | st[8192]
  char* ws = (char*)d_ws;
  u16*   zb      = (u16*)ws;
  float* m_part  = (float*)(ws + (size_t)NTOT * DD * 2);
  float* l_part  = m_part + COLSPLIT * NTOT;
  float* st_part = l_part + COLSPLIT * NTOT;

  ntx_convert<<<dim3((NTOT * DD) / (256 * 4)), dim3(256), 0, stream>>>(z1, z2, zb, out);
  ntx_main<<<dim3(NTOT / ROWS_PER_BLOCK, COLSPLIT), dim3(256), 0, stream>>>(
      zb, m_part, l_part, st_part);
  ntx_finish<<<dim3(NTOT / 256), dim3(256), 0, stream>>>(m_part, l_part, st_part, out);
}